// Round 11
// baseline (228.879 us; speedup 1.0000x reference)
//
#include <hip/hip_runtime.h>
#include <hip/hip_bf16.h>

// 2-layer GCN, N=100000, E=1200000, dims 64, fp32 in/out.
//
// R21 = R20 resubmitted (R10 bench died in infra: "container failed
// twice", same transient as R6->R7; swizzle/feature-coverage re-audited,
// no defect).
// R20: two-pass half-row agg gathers. fagg phase 1 runs TWO passes over
// each node's edge list; pass p gathers only bytes [64p, 64p+64) of each
// source row (one full cache line, zero waste). Distinct-line footprint
// per pass = 6.4MB (vs 12.8) -> L2 hit rate up, FETCH down. Per-feature
// summation order unchanged -> bit-identical results (absmax 0.00390625).
// esrc walked twice (2nd pass L2-hot). LDS transpose: lane h8 pass p ->
// uint2 slot q=8p+h8 (uint4 entry q>>1, XOR swizzle); phase-2 GEMM
// untouched. k_part / k_csr(+fused GEMM1) / heavy-first banding: R19.

#define FEAT 64
#define CAP 9216

typedef __attribute__((ext_vector_type(8))) short bf16x8;
typedef __attribute__((ext_vector_type(4))) float f32x4;
union BF8 { bf16x8 v; unsigned short u[8]; unsigned pk[4]; uint4 q; };

__device__ __forceinline__ unsigned short f2bf(float f) {
    unsigned u = __float_as_uint(f);
    return (unsigned short)((u + 0x7FFFu + ((u >> 16) & 1u)) >> 16);   // RNE
}
__device__ __forceinline__ float bflo(unsigned u) { return __uint_as_float(u << 16); }
__device__ __forceinline__ float bfhi(unsigned u) { return __uint_as_float(u & 0xFFFF0000u); }
__device__ __forceinline__ unsigned pk2bf(float a, float b) {   // v_cvt_pk_bf16_f32
    union { __hip_bfloat162 b; unsigned u; } cv;
    cv.b = __float22bfloat162_rn(make_float2(a, b));
    return cv.u;
}

// ---- partition edges into fixed-capacity buckets (src<<9 | dst&511);
// tail blocks pack W into MFMA B-frag layout (column-permuted).
__global__ void __launch_bounds__(256)
k_part(const int* __restrict__ src, const int* __restrict__ dst,
       int* __restrict__ bcnt, unsigned* __restrict__ buckets, int E, int pblocks,
       const float* __restrict__ W1, const float* __restrict__ W2,
       const float* __restrict__ Wl, unsigned short* __restrict__ P) {
    if ((int)blockIdx.x >= pblocks) {
        int widx = blockIdx.x - pblocks;
        const float* W = (widx == 0) ? W1 : (widx == 1) ? W2 : Wl;
        unsigned short* p = P + widx * 4096;
        for (int i = threadIdx.x; i < 4096; i += 256) {
            int c = i >> 10, s = (i >> 9) & 1, l = (i >> 3) & 63, j = i & 7;
            int k = s * 32 + ((l >> 4) << 3) + j;
            int col = ((l & 15) << 2) + c;      // lane m -> output cols 4m..4m+3
            p[i] = f2bf(W[k * 64 + col]);
        }
        return;
    }
    __shared__ unsigned pk[4096];
    __shared__ unsigned char bk[4096];
    __shared__ int h[256];
    __shared__ int cur[256];
    int tid = threadIdx.x;
    h[tid] = 0;
    __syncthreads();
    int base = blockIdx.x * 4096;
#pragma unroll
    for (int i = 0; i < 16; ++i) {
        int li = i * 256 + tid;
        int e = base + li;
        if (e < E) {
            int s = src[e], d = dst[e];
            int b = d >> 9;
            pk[li] = ((unsigned)s << 9) | ((unsigned)d & 511u);
            bk[li] = (unsigned char)b;
            atomicAdd(&h[b], 1);
        } else {
            bk[li] = 255;
        }
    }
    __syncthreads();
    {
        int c = h[tid];
        int run = c ? atomicAdd(&bcnt[tid], c) : 0;   // reserve [run, run+c)
        cur[tid] = run;
    }
    __syncthreads();
#pragma unroll
    for (int i = 0; i < 16; ++i) {
        int li = i * 256 + tid;
        int e = base + li;
        if (e < E) {
            int b = bk[li];
            int pos = atomicAdd(&cur[b], 1);
            buckets[(size_t)b * CAP + pos] = pk[li];
        }
    }
}

// ---- per-bucket CSR finish + degree counting-sort + FUSED layer-1 GEMM.
__global__ void __launch_bounds__(512)
k_csr(const unsigned* __restrict__ buckets, const int* __restrict__ bcnt,
      const float* __restrict__ x, const unsigned short* __restrict__ Wpk,
      unsigned short* __restrict__ Hs1, int* __restrict__ esrc,
      int* __restrict__ perm, int2* __restrict__ pofs, float* __restrict__ pdinv,
      int n) {
    __shared__ int hist[512];
    __shared__ int cur[512];
    __shared__ int dh[64];
    __shared__ int dbase[64];
    __shared__ int dcur[64];
    __shared__ float sdinv[512];
    int tid = threadIdx.x;
    int b = blockIdx.x;
    hist[tid] = 0;
    if (tid < 64) dh[tid] = 0;
    __syncthreads();
    int cnt = bcnt[b];
    size_t beg = (size_t)b * CAP;
    for (int j = tid; j < cnt; j += 512)
        atomicAdd(&hist[buckets[beg + j] & 511u], 1);
    __syncthreads();
    int v = hist[tid];
    for (int off = 1; off < 512; off <<= 1) {        // inclusive scan
        int xs = (tid >= off) ? hist[tid - off] : 0;
        __syncthreads();
        hist[tid] += xs;
        __syncthreads();
    }
    int excl = hist[tid] - v;
    int node = (b << 9) + tid;
    bool valid = node < n;
    float di = rsqrtf((float)v + 1.0f);
    sdinv[tid] = di;
    if (valid) atomicAdd(&dh[min(v, 63)], 1);
    cur[tid] = excl;
    __syncthreads();
    if (tid == 0) {
        int run = 0;
        for (int i = 0; i < 64; ++i) { dbase[i] = run; run += dh[i]; dcur[i] = 0; }
    }
    __syncthreads();
    if (valid) {
        int bin = min(v, 63);
        int r = atomicAdd(&dcur[bin], 1);
        int gs = (b << 9) + dbase[bin] + r;          // compacted: slot<n iff valid
        perm[gs] = node;
        pofs[gs] = make_int2((int)beg + excl, (int)beg + excl + v);
        pdinv[gs] = di;
    }
    for (int j = tid; j < cnt; j += 512) {
        unsigned u = buckets[beg + j];
        int loc = (int)(u & 511u);
        int r = atomicAdd(&cur[loc], 1);
        esrc[beg + r] = (int)(u >> 9);
    }
    // ---- fused layer-1 GEMM (sdinv synced by the barriers above) ----
    int lane = tid & 63;
    int wv = tid >> 6;
    BF8 bfr[8];
    const uint4* wp = (const uint4*)Wpk;
#pragma unroll
    for (int f = 0; f < 8; ++f) bfr[f].q = wp[f * 64 + lane];
    int mrow = lane & 15, kq = lane >> 4, colb = lane & 15;
    for (int t = wv; t < 32; t += 8) {
        int rb = (b << 9) + (t << 4);
        int row = rb + mrow;
        bool ok = row < n;
        BF8 a0, a1;
        const float4* xr = (const float4*)(x + ((unsigned)row << 6));
        float4 z = make_float4(0.f, 0.f, 0.f, 0.f);
        float4 p0 = ok ? xr[kq * 2]     : z;
        float4 p1 = ok ? xr[kq * 2 + 1] : z;
        float4 p2 = ok ? xr[8 + kq * 2] : z;
        float4 p3 = ok ? xr[8 + kq * 2 + 1] : z;
        a0.pk[0] = pk2bf(p0.x, p0.y); a0.pk[1] = pk2bf(p0.z, p0.w);
        a0.pk[2] = pk2bf(p1.x, p1.y); a0.pk[3] = pk2bf(p1.z, p1.w);
        a1.pk[0] = pk2bf(p2.x, p2.y); a1.pk[1] = pk2bf(p2.z, p2.w);
        a1.pk[2] = pk2bf(p3.x, p3.y); a1.pk[3] = pk2bf(p3.z, p3.w);
        f32x4 acc0 = {0.f, 0.f, 0.f, 0.f}, acc1 = acc0, acc2 = acc0, acc3 = acc0;
        acc0 = __builtin_amdgcn_mfma_f32_16x16x32_bf16(a0.v, bfr[0].v, acc0, 0, 0, 0);
        acc0 = __builtin_amdgcn_mfma_f32_16x16x32_bf16(a1.v, bfr[1].v, acc0, 0, 0, 0);
        acc1 = __builtin_amdgcn_mfma_f32_16x16x32_bf16(a0.v, bfr[2].v, acc1, 0, 0, 0);
        acc1 = __builtin_amdgcn_mfma_f32_16x16x32_bf16(a1.v, bfr[3].v, acc1, 0, 0, 0);
        acc2 = __builtin_amdgcn_mfma_f32_16x16x32_bf16(a0.v, bfr[4].v, acc2, 0, 0, 0);
        acc2 = __builtin_amdgcn_mfma_f32_16x16x32_bf16(a1.v, bfr[5].v, acc2, 0, 0, 0);
        acc3 = __builtin_amdgcn_mfma_f32_16x16x32_bf16(a0.v, bfr[6].v, acc3, 0, 0, 0);
        acc3 = __builtin_amdgcn_mfma_f32_16x16x32_bf16(a1.v, bfr[7].v, acc3, 0, 0, 0);
        int rowb = rb + (kq << 2);
        int lrow = (t << 4) + (kq << 2);
#pragma unroll
        for (int i = 0; i < 4; ++i) {
            if (rowb + i >= n) break;
            float sc = sdinv[lrow + i];
            unsigned ro = (unsigned)(rowb + i) << 6;
            uint2 o = make_uint2(pk2bf(acc0[i] * sc, acc1[i] * sc),
                                 pk2bf(acc2[i] * sc, acc3[i] * sc));
            *(uint2*)(Hs1 + ro + (colb << 2)) = o;
        }
    }
}

#define ACC4(H, W) \
    a0 = fmaf(bflo(H.x), W, a0); a1 = fmaf(bfhi(H.x), W, a1); \
    a2 = fmaf(bflo(H.y), W, a2); a3 = fmaf(bfhi(H.y), W, a3);

#define GROW2(s) (*(const uint2*)(HP + ((unsigned)(s) << 6) + (h8 << 2)))

#define HALF2(hX0, hX1, hX2, hX3, sX0, sX1, sX2, sX3, wX0, wX1, wX2, wX3) \
    {                                                                     \
        int jn = j + 8;                                                   \
        int n0 = sX0, n1 = sX1, n2 = sX2, n3 = sX3;                       \
        float v0 = 0.f, v1 = 0.f, v2 = 0.f, v3 = 0.f;                     \
        if (jn     < end) { n0 = esrc[jn];     v0 = 1.f; }                \
        if (jn + 1 < end) { n1 = esrc[jn + 1]; v1 = 1.f; }                \
        if (jn + 2 < end) { n2 = esrc[jn + 2]; v2 = 1.f; }                \
        if (jn + 3 < end) { n3 = esrc[jn + 3]; v3 = 1.f; }                \
        ACC4(hX0, wX0) ACC4(hX1, wX1) ACC4(hX2, wX2) ACC4(hX3, wX3)       \
        hX0 = GROW2(n0); hX1 = GROW2(n1); hX2 = GROW2(n2); hX3 = GROW2(n3); \
        sX0 = n0; sX1 = n1; sX2 = n2; sX3 = n3;                           \
        wX0 = v0; wX1 = v1; wX2 = v2; wX3 = v3;                           \
        j += 4;                                                           \
    }

// ---- FUSED aggregation + GEMM.
// Block = 32 consecutive degree-sorted slots of bucket q, degree-band
// L = 15 - blk/NB (heavy-first). Phase 1: TWO passes over the edge list;
// pass p gathers 64B half-rows (8 lanes x uint2), 2-deep ping-pong
// pipeline, weight-0 fmaf masking, register accumulation; per-pass
// epilogue packs 4 bf16 into the XOR-swizzled LDS row (slot q=8p+h8).
// Phase 2: 4 MFMAs/wave; bf16 (*pdinv) or fp32 (+bias2) out via perm.
template <bool RELU, bool OUT_F32>
__global__ void __launch_bounds__(256)
k_fagg(const int* __restrict__ perm, const int2* __restrict__ pofs,
       const float* __restrict__ pdinv, const int* __restrict__ esrc,
       const unsigned short* __restrict__ Hs, const float* __restrict__ bias1,
       const unsigned short* __restrict__ Wpk, const float* __restrict__ bias2,
       void* __restrict__ outv, int nbuck, int n) {
    __shared__ uint4 lds_a[32][8];
    int tid = threadIdx.x;
    int lane = tid & 63;
    int wv = tid >> 6;
    int h8 = lane & 7;
    int q = blockIdx.x % nbuck;                  // bucket
    int L = 15 - blockIdx.x / nbuck;             // degree band, heavy first
    int sbase = (q << 9) + (L << 5);
    int rl = (wv << 3) + (lane >> 3);            // local row 0..31
    int slot = sbase + rl;
    bool ok = slot < n;
    int node = 0, beg = 0, end = 0;
    float dd = 0.f;
    if (ok) {
        node = perm[slot];
        int2 oe = pofs[slot];
        beg = oe.x; end = oe.y;
        dd = pdinv[slot];
    }
    uint2* row2 = (uint2*)(&lds_a[rl][0]);
#pragma unroll
    for (int p = 0; p < 2; ++p) {
        const unsigned short* HP = Hs + (p << 5);     // half-row base (shorts)
        float a0 = 0.f, a1 = 0.f, a2 = 0.f, a3 = 0.f;
        int j = beg;
        int sA0 = 0, sA1 = 0, sA2 = 0, sA3 = 0;
        float wA0 = 0.f, wA1 = 0.f, wA2 = 0.f, wA3 = 0.f;
        if (j     < end) { sA0 = esrc[j];     wA0 = 1.f; }
        if (j + 1 < end) { sA1 = esrc[j + 1]; wA1 = 1.f; }
        if (j + 2 < end) { sA2 = esrc[j + 2]; wA2 = 1.f; }
        if (j + 3 < end) { sA3 = esrc[j + 3]; wA3 = 1.f; }
        int sB0 = sA0, sB1 = sA1, sB2 = sA2, sB3 = sA3;
        float wB0 = 0.f, wB1 = 0.f, wB2 = 0.f, wB3 = 0.f;
        if (j + 4 < end) { sB0 = esrc[j + 4]; wB0 = 1.f; }
        if (j + 5 < end) { sB1 = esrc[j + 5]; wB1 = 1.f; }
        if (j + 6 < end) { sB2 = esrc[j + 6]; wB2 = 1.f; }
        if (j + 7 < end) { sB3 = esrc[j + 7]; wB3 = 1.f; }
        uint2 hA0 = GROW2(sA0), hA1 = GROW2(sA1), hA2 = GROW2(sA2), hA3 = GROW2(sA3);
        uint2 hB0 = GROW2(sB0), hB1 = GROW2(sB1), hB2 = GROW2(sB2), hB3 = GROW2(sB3);
        while (__ballot(j < end)) {
            HALF2(hA0, hA1, hA2, hA3, sA0, sA1, sA2, sA3, wA0, wA1, wA2, wA3)
            if (!__ballot(j < end)) break;
            HALF2(hB0, hB1, hB2, hB3, sB0, sB1, sB2, sB3, wB0, wB1, wB2, wB3)
        }
        uint2 pk2 = make_uint2(0, 0);
        if (ok) {
            uint2 sv = *(const uint2*)(HP + ((unsigned)node << 6) + (h8 << 2));
            float4 bb = ((const float4*)bias1)[(p << 3) + h8];   // feats 32p+4h8..+3
            float r0 = (a0 + bflo(sv.x)) * dd + bb.x;
            float r1 = (a1 + bfhi(sv.x)) * dd + bb.y;
            float r2 = (a2 + bflo(sv.y)) * dd + bb.z;
            float r3 = (a3 + bfhi(sv.y)) * dd + bb.w;
            if (RELU) {
                r0 = fmaxf(r0, 0.f); r1 = fmaxf(r1, 0.f);
                r2 = fmaxf(r2, 0.f); r3 = fmaxf(r3, 0.f);
            }
            pk2 = make_uint2(pk2bf(r0, r1), pk2bf(r2, r3));
        }
        int qq = (p << 3) + h8;                       // uint2 slot in row
        row2[(((qq >> 1) ^ (rl & 7)) << 1) + (qq & 1)] = pk2;   // XOR swizzle
    }
    __syncthreads();
    // ---- phase 2: GEMM on the block's 32 rows ----
    int hh = wv & 1, tt = wv >> 1;
    BF8 bq0, bq1, bq2, bq3;
    {
        const uint4* wp = (const uint4*)Wpk;
        bq0.q = wp[(4 * hh + 0) * 64 + lane];
        bq1.q = wp[(4 * hh + 1) * 64 + lane];
        bq2.q = wp[(4 * hh + 2) * 64 + lane];
        bq3.q = wp[(4 * hh + 3) * 64 + lane];
    }
    int mr = lane & 15, kq = lane >> 4, colb = lane & 15;
    int rloc = tt * 16 + mr;
    BF8 fa0, fa1;
    fa0.q = lds_a[rloc][kq ^ (rloc & 7)];
    fa1.q = lds_a[rloc][(kq + 4) ^ (rloc & 7)];
    f32x4 accA = {0.f, 0.f, 0.f, 0.f}, accB = accA;
    accA = __builtin_amdgcn_mfma_f32_16x16x32_bf16(fa0.v, bq0.v, accA, 0, 0, 0);
    accA = __builtin_amdgcn_mfma_f32_16x16x32_bf16(fa1.v, bq1.v, accA, 0, 0, 0);
    accB = __builtin_amdgcn_mfma_f32_16x16x32_bf16(fa0.v, bq2.v, accB, 0, 0, 0);
    accB = __builtin_amdgcn_mfma_f32_16x16x32_bf16(fa1.v, bq3.v, accB, 0, 0, 0);
    float b2x = 0.f, b2y = 0.f;
    if (OUT_F32) {
        b2x = bias2[(colb << 2) + (hh << 1)];
        b2y = bias2[(colb << 2) + (hh << 1) + 1];
    }
    int rowb = tt * 16 + (kq << 2);
#pragma unroll
    for (int i = 0; i < 4; ++i) {
        int sl = sbase + rowb + i;
        if (sl >= n) continue;
        int orow = perm[sl];
        if (OUT_F32) {
            float2 o = make_float2(accA[i] + b2x, accB[i] + b2y);
            *(float2*)((float*)outv + ((unsigned)orow << 6) + (colb << 2) + (hh << 1)) = o;
        } else {
            float sc = pdinv[sl];
            unsigned o = pk2bf(accA[i] * sc, accB[i] * sc);
            *(unsigned*)((unsigned short*)outv + ((unsigned)orow << 6) + (colb << 2) + (hh << 1)) = o;
        }
    }
}

extern "C" void kernel_launch(void* const* d_in, const int* in_sizes, int n_in,
                              void* d_out, int out_size, void* d_ws, size_t ws_size,
                              hipStream_t stream) {
    const float* x  = (const float*)d_in[0];
    const int*   ei = (const int*)d_in[1];   // [2][E] int32
    const float* W1 = (const float*)d_in[2];
    const float* b1 = (const float*)d_in[3];
    const float* W2 = (const float*)d_in[4];
    const float* b2 = (const float*)d_in[5];
    const float* Wl = (const float*)d_in[6];
    const float* bl = (const float*)d_in[7];
    float* out = (float*)d_out;

    const int n = in_sizes[0] / FEAT;   // 100000
    const int E = in_sizes[1] / 2;      // 1200000
    const int* src = ei;
    const int* dst = ei + E;

    const int B = 256;
    const int NB = (n + 511) >> 9;            // 196 buckets
    const int pblocks = (E + 4095) / 4096;
    const int fagg_blocks = NB * 16;          // 16 degree-bands x 32 slots per bucket

    char* w = (char*)d_ws;
    int*   bcnt     = (int*)w;              w += 256 * 4;
    float* pdinv    = (float*)w;            w += (size_t)n * 4;
    int*   perm     = (int*)w;              w += (size_t)n * 4;
    w = (char*)(((uintptr_t)w + 15) & ~(uintptr_t)15);
    int2*  pofs     = (int2*)w;             w += (size_t)n * 8;
    unsigned short* Wpk = (unsigned short*)w;  w += 3 * 4096 * 2;
    w = (char*)(((uintptr_t)w + 15) & ~(uintptr_t)15);
    unsigned* buckets = (unsigned*)w;       w += (size_t)NB * CAP * 4;
    int*   esrc     = (int*)w;              w += (size_t)NB * CAP * 4;
    unsigned short* bufA = (unsigned short*)w;  w += (size_t)n * FEAT * 2;  // Hs1
    unsigned short* bufB = (unsigned short*)w;                              // Hs3

    // ---- CSR build + fused layer-1 GEMM ----
    hipMemsetAsync(bcnt, 0, 256 * 4, stream);
    k_part<<<dim3(pblocks + 3), dim3(B), 0, stream>>>(src, dst, bcnt, buckets, E,
                                                      pblocks, W1, W2, Wl, Wpk);
    k_csr<<<dim3(NB), dim3(512), 0, stream>>>(buckets, bcnt, x, Wpk, bufA,
                                              esrc, perm, pofs, pdinv, n);

    // ---- fused layer-1 agg + layer-2 GEMM: Hs3 = (relu(agg(Hs1)+b1)@W2)*dinv ----
    k_fagg<true, false><<<dim3(fagg_blocks), dim3(B), 0, stream>>>(
        perm, pofs, pdinv, esrc, bufA, b1, Wpk + 4096, nullptr, bufB, NB, n);

    // ---- fused layer-2 agg + final linear: out = (agg(Hs3)+b2)@Wl + bl ----
    k_fagg<false, true><<<dim3(fagg_blocks), dim3(B), 0, stream>>>(
        perm, pofs, pdinv, esrc, bufB, b2, Wpk + 8192, bl, out, NB, n);
}

// Round 12
// 203.590 us; speedup vs baseline: 1.1242x; 1.1242x over previous
//
#include <hip/hip_runtime.h>
#include <hip/hip_bf16.h>

// 2-layer GCN, N=100000, E=1200000, dims 64, fp32 in/out.
//
// R22 = R19 reverted (proven 203.1us best).
// R21 (two-pass half-row gathers) regressed: FETCH rose 130->137MB
// (inter-block pass drift keeps both half-footprints live; no L2 gain),
// 2x gather instructions + 2x esrc walks (VALU 17->23%), +100K LDS bank
// conflicts. Fabric rate pinned at ~3.4 TB/s across R14/R19/R21's three
// different gather structures -> random line-granular service ceiling.
// Agg floor at that ceiling: 154MB/layer, >=106MB L2-miss @3.4TB/s ~35us
// per agg; R19 runs ~40. LESSON: don't split full-line gathers.
// R19 = R17 + block = 32 consecutive degree-sorted slots (waves share a
// degree band -> no max-over-quarters barrier waste) + heavy-first LPT
// dispatch. k_part(+Wpack) / k_csr(+degree-sort+fused GEMM1) as R17.

#define FEAT 64
#define CAP 9216

typedef __attribute__((ext_vector_type(8))) short bf16x8;
typedef __attribute__((ext_vector_type(4))) float f32x4;
union BF8 { bf16x8 v; unsigned short u[8]; unsigned pk[4]; uint4 q; };

__device__ __forceinline__ unsigned short f2bf(float f) {
    unsigned u = __float_as_uint(f);
    return (unsigned short)((u + 0x7FFFu + ((u >> 16) & 1u)) >> 16);   // RNE
}
__device__ __forceinline__ float bflo(unsigned u) { return __uint_as_float(u << 16); }
__device__ __forceinline__ float bfhi(unsigned u) { return __uint_as_float(u & 0xFFFF0000u); }
__device__ __forceinline__ unsigned pk2bf(float a, float b) {   // v_cvt_pk_bf16_f32
    union { __hip_bfloat162 b; unsigned u; } cv;
    cv.b = __float22bfloat162_rn(make_float2(a, b));
    return cv.u;
}

// ---- partition edges into fixed-capacity buckets (src<<9 | dst&511);
// tail blocks pack W into MFMA B-frag layout (column-permuted).
__global__ void __launch_bounds__(256)
k_part(const int* __restrict__ src, const int* __restrict__ dst,
       int* __restrict__ bcnt, unsigned* __restrict__ buckets, int E, int pblocks,
       const float* __restrict__ W1, const float* __restrict__ W2,
       const float* __restrict__ Wl, unsigned short* __restrict__ P) {
    if ((int)blockIdx.x >= pblocks) {
        int widx = blockIdx.x - pblocks;
        const float* W = (widx == 0) ? W1 : (widx == 1) ? W2 : Wl;
        unsigned short* p = P + widx * 4096;
        for (int i = threadIdx.x; i < 4096; i += 256) {
            int c = i >> 10, s = (i >> 9) & 1, l = (i >> 3) & 63, j = i & 7;
            int k = s * 32 + ((l >> 4) << 3) + j;
            int col = ((l & 15) << 2) + c;      // lane m -> output cols 4m..4m+3
            p[i] = f2bf(W[k * 64 + col]);
        }
        return;
    }
    __shared__ unsigned pk[4096];
    __shared__ unsigned char bk[4096];
    __shared__ int h[256];
    __shared__ int cur[256];
    int tid = threadIdx.x;
    h[tid] = 0;
    __syncthreads();
    int base = blockIdx.x * 4096;
#pragma unroll
    for (int i = 0; i < 16; ++i) {
        int li = i * 256 + tid;
        int e = base + li;
        if (e < E) {
            int s = src[e], d = dst[e];
            int b = d >> 9;
            pk[li] = ((unsigned)s << 9) | ((unsigned)d & 511u);
            bk[li] = (unsigned char)b;
            atomicAdd(&h[b], 1);
        } else {
            bk[li] = 255;
        }
    }
    __syncthreads();
    {
        int c = h[tid];
        int run = c ? atomicAdd(&bcnt[tid], c) : 0;   // reserve [run, run+c)
        cur[tid] = run;
    }
    __syncthreads();
#pragma unroll
    for (int i = 0; i < 16; ++i) {
        int li = i * 256 + tid;
        int e = base + li;
        if (e < E) {
            int b = bk[li];
            int pos = atomicAdd(&cur[b], 1);
            buckets[(size_t)b * CAP + pos] = pk[li];
        }
    }
}

// ---- per-bucket CSR finish + degree counting-sort + FUSED layer-1 GEMM.
// CSR: node hist -> scan -> degree-sort -> perm/pofs/pdinv + esrc scatter.
// GEMM tail: Hs1[row] = (x[row]@W1)*dinv[row] for the bucket's 512 rows
// (8 waves x 4 tiles of 16 rows; dinv via LDS sdinv).
__global__ void __launch_bounds__(512)
k_csr(const unsigned* __restrict__ buckets, const int* __restrict__ bcnt,
      const float* __restrict__ x, const unsigned short* __restrict__ Wpk,
      unsigned short* __restrict__ Hs1, int* __restrict__ esrc,
      int* __restrict__ perm, int2* __restrict__ pofs, float* __restrict__ pdinv,
      int n) {
    __shared__ int hist[512];
    __shared__ int cur[512];
    __shared__ int dh[64];
    __shared__ int dbase[64];
    __shared__ int dcur[64];
    __shared__ float sdinv[512];
    int tid = threadIdx.x;
    int b = blockIdx.x;
    hist[tid] = 0;
    if (tid < 64) dh[tid] = 0;
    __syncthreads();
    int cnt = bcnt[b];
    size_t beg = (size_t)b * CAP;
    for (int j = tid; j < cnt; j += 512)
        atomicAdd(&hist[buckets[beg + j] & 511u], 1);
    __syncthreads();
    int v = hist[tid];
    for (int off = 1; off < 512; off <<= 1) {        // inclusive scan
        int xs = (tid >= off) ? hist[tid - off] : 0;
        __syncthreads();
        hist[tid] += xs;
        __syncthreads();
    }
    int excl = hist[tid] - v;
    int node = (b << 9) + tid;
    bool valid = node < n;
    float di = rsqrtf((float)v + 1.0f);
    sdinv[tid] = di;
    if (valid) atomicAdd(&dh[min(v, 63)], 1);
    cur[tid] = excl;
    __syncthreads();
    if (tid == 0) {
        int run = 0;
        for (int i = 0; i < 64; ++i) { dbase[i] = run; run += dh[i]; dcur[i] = 0; }
    }
    __syncthreads();
    if (valid) {
        int bin = min(v, 63);
        int r = atomicAdd(&dcur[bin], 1);
        int gs = (b << 9) + dbase[bin] + r;          // compacted: slot<n iff valid
        perm[gs] = node;
        pofs[gs] = make_int2((int)beg + excl, (int)beg + excl + v);
        pdinv[gs] = di;
    }
    for (int j = tid; j < cnt; j += 512) {
        unsigned u = buckets[beg + j];
        int loc = (int)(u & 511u);
        int r = atomicAdd(&cur[loc], 1);
        esrc[beg + r] = (int)(u >> 9);
    }
    // ---- fused layer-1 GEMM (sdinv synced by the barriers above) ----
    int lane = tid & 63;
    int wv = tid >> 6;
    BF8 bfr[8];
    const uint4* wp = (const uint4*)Wpk;
#pragma unroll
    for (int f = 0; f < 8; ++f) bfr[f].q = wp[f * 64 + lane];
    int mrow = lane & 15, kq = lane >> 4, colb = lane & 15;
    for (int t = wv; t < 32; t += 8) {
        int rb = (b << 9) + (t << 4);
        int row = rb + mrow;
        bool ok = row < n;
        BF8 a0, a1;
        const float4* xr = (const float4*)(x + ((unsigned)row << 6));
        float4 z = make_float4(0.f, 0.f, 0.f, 0.f);
        float4 p0 = ok ? xr[kq * 2]     : z;
        float4 p1 = ok ? xr[kq * 2 + 1] : z;
        float4 p2 = ok ? xr[8 + kq * 2] : z;
        float4 p3 = ok ? xr[8 + kq * 2 + 1] : z;
        a0.pk[0] = pk2bf(p0.x, p0.y); a0.pk[1] = pk2bf(p0.z, p0.w);
        a0.pk[2] = pk2bf(p1.x, p1.y); a0.pk[3] = pk2bf(p1.z, p1.w);
        a1.pk[0] = pk2bf(p2.x, p2.y); a1.pk[1] = pk2bf(p2.z, p2.w);
        a1.pk[2] = pk2bf(p3.x, p3.y); a1.pk[3] = pk2bf(p3.z, p3.w);
        f32x4 acc0 = {0.f, 0.f, 0.f, 0.f}, acc1 = acc0, acc2 = acc0, acc3 = acc0;
        acc0 = __builtin_amdgcn_mfma_f32_16x16x32_bf16(a0.v, bfr[0].v, acc0, 0, 0, 0);
        acc0 = __builtin_amdgcn_mfma_f32_16x16x32_bf16(a1.v, bfr[1].v, acc0, 0, 0, 0);
        acc1 = __builtin_amdgcn_mfma_f32_16x16x32_bf16(a0.v, bfr[2].v, acc1, 0, 0, 0);
        acc1 = __builtin_amdgcn_mfma_f32_16x16x32_bf16(a1.v, bfr[3].v, acc1, 0, 0, 0);
        acc2 = __builtin_amdgcn_mfma_f32_16x16x32_bf16(a0.v, bfr[4].v, acc2, 0, 0, 0);
        acc2 = __builtin_amdgcn_mfma_f32_16x16x32_bf16(a1.v, bfr[5].v, acc2, 0, 0, 0);
        acc3 = __builtin_amdgcn_mfma_f32_16x16x32_bf16(a0.v, bfr[6].v, acc3, 0, 0, 0);
        acc3 = __builtin_amdgcn_mfma_f32_16x16x32_bf16(a1.v, bfr[7].v, acc3, 0, 0, 0);
        int rowb = rb + (kq << 2);
        int lrow = (t << 4) + (kq << 2);
#pragma unroll
        for (int i = 0; i < 4; ++i) {
            if (rowb + i >= n) break;
            float sc = sdinv[lrow + i];
            unsigned ro = (unsigned)(rowb + i) << 6;
            uint2 o = make_uint2(pk2bf(acc0[i] * sc, acc1[i] * sc),
                                 pk2bf(acc2[i] * sc, acc3[i] * sc));
            *(uint2*)(Hs1 + ro + (colb << 2)) = o;
        }
    }
}

#define ACC8(H, W) \
    a0 = fmaf(bflo(H.x), W, a0); a1 = fmaf(bfhi(H.x), W, a1); \
    a2 = fmaf(bflo(H.y), W, a2); a3 = fmaf(bfhi(H.y), W, a3); \
    a4 = fmaf(bflo(H.z), W, a4); a5 = fmaf(bfhi(H.z), W, a5); \
    a6 = fmaf(bflo(H.w), W, a6); a7 = fmaf(bfhi(H.w), W, a7);

#define GROW(s) (*(const uint4*)(Hs + ((unsigned)(s) << 6) + (h8 << 3)))

#define HALF(hX0, hX1, hX2, hX3, sX0, sX1, sX2, sX3, wX0, wX1, wX2, wX3)  \
    {                                                                     \
        int jn = j + 8;                                                   \
        int n0 = sX0, n1 = sX1, n2 = sX2, n3 = sX3;                       \
        float v0 = 0.f, v1 = 0.f, v2 = 0.f, v3 = 0.f;                     \
        if (jn     < end) { n0 = esrc[jn];     v0 = 1.f; }                \
        if (jn + 1 < end) { n1 = esrc[jn + 1]; v1 = 1.f; }                \
        if (jn + 2 < end) { n2 = esrc[jn + 2]; v2 = 1.f; }                \
        if (jn + 3 < end) { n3 = esrc[jn + 3]; v3 = 1.f; }                \
        ACC8(hX0, wX0) ACC8(hX1, wX1) ACC8(hX2, wX2) ACC8(hX3, wX3)       \
        hX0 = GROW(n0); hX1 = GROW(n1); hX2 = GROW(n2); hX3 = GROW(n3);   \
        sX0 = n0; sX1 = n1; sX2 = n2; sX3 = n3;                           \
        wX0 = v0; wX1 = v1; wX2 = v2; wX3 = v3;                           \
        j += 4;                                                           \
    }

// ---- FUSED aggregation + GEMM.
// Block = 32 CONSECUTIVE degree-sorted slots of bucket q, degree-band
// L = 15 - blk/NB (heavy-first LPT dispatch). All 4 waves sit in the same
// degree band -> minimal max-over-waves barrier waste. Phase 1: 8 slots/
// wave x 8 lanes, 2-deep ping-pong gather pipeline, weight-0 fmaf masking,
// register accumulation. Phase 2: LDS transpose (XOR swizzle) -> 4 MFMAs/
// wave; bf16 (*pdinv) or fp32 (+bias2) output scattered via perm.
template <bool RELU, bool OUT_F32>
__global__ void __launch_bounds__(256)
k_fagg(const int* __restrict__ perm, const int2* __restrict__ pofs,
       const float* __restrict__ pdinv, const int* __restrict__ esrc,
       const unsigned short* __restrict__ Hs, const float* __restrict__ bias1,
       const unsigned short* __restrict__ Wpk, const float* __restrict__ bias2,
       void* __restrict__ outv, int nbuck, int n) {
    __shared__ uint4 lds_a[32][8];
    int tid = threadIdx.x;
    int lane = tid & 63;
    int wv = tid >> 6;
    int h8 = lane & 7;
    int q = blockIdx.x % nbuck;                  // bucket
    int L = 15 - blockIdx.x / nbuck;             // degree band, heavy first
    int sbase = (q << 9) + (L << 5);
    int rl = (wv << 3) + (lane >> 3);            // local row 0..31
    int slot = sbase + rl;
    bool ok = slot < n;
    int node = 0, beg = 0, end = 0;
    float dd = 0.f;
    if (ok) {
        node = perm[slot];
        int2 oe = pofs[slot];
        beg = oe.x; end = oe.y;
        dd = pdinv[slot];
    }
    float a0 = 0.f, a1 = 0.f, a2 = 0.f, a3 = 0.f, a4 = 0.f, a5 = 0.f, a6 = 0.f, a7 = 0.f;
    {
        int j = beg;
        int sA0 = 0, sA1 = 0, sA2 = 0, sA3 = 0;
        float wA0 = 0.f, wA1 = 0.f, wA2 = 0.f, wA3 = 0.f;
        if (j     < end) { sA0 = esrc[j];     wA0 = 1.f; }
        if (j + 1 < end) { sA1 = esrc[j + 1]; wA1 = 1.f; }
        if (j + 2 < end) { sA2 = esrc[j + 2]; wA2 = 1.f; }
        if (j + 3 < end) { sA3 = esrc[j + 3]; wA3 = 1.f; }
        int sB0 = sA0, sB1 = sA1, sB2 = sA2, sB3 = sA3;
        float wB0 = 0.f, wB1 = 0.f, wB2 = 0.f, wB3 = 0.f;
        if (j + 4 < end) { sB0 = esrc[j + 4]; wB0 = 1.f; }
        if (j + 5 < end) { sB1 = esrc[j + 5]; wB1 = 1.f; }
        if (j + 6 < end) { sB2 = esrc[j + 6]; wB2 = 1.f; }
        if (j + 7 < end) { sB3 = esrc[j + 7]; wB3 = 1.f; }
        uint4 hA0 = GROW(sA0), hA1 = GROW(sA1), hA2 = GROW(sA2), hA3 = GROW(sA3);
        uint4 hB0 = GROW(sB0), hB1 = GROW(sB1), hB2 = GROW(sB2), hB3 = GROW(sB3);
        while (__ballot(j < end)) {
            HALF(hA0, hA1, hA2, hA3, sA0, sA1, sA2, sA3, wA0, wA1, wA2, wA3)
            if (!__ballot(j < end)) break;
            HALF(hB0, hB1, hB2, hB3, sB0, sB1, sB2, sB3, wB0, wB1, wB2, wB3)
        }
    }
    uint4 packed = make_uint4(0, 0, 0, 0);
    if (ok) {
        uint4 sv = *(const uint4*)(Hs + ((unsigned)node << 6) + (h8 << 3));
        const float4* b4 = (const float4*)bias1;
        float4 bA = b4[h8 * 2], bB = b4[h8 * 2 + 1];
        float r0 = (a0 + bflo(sv.x)) * dd + bA.x;
        float r1 = (a1 + bfhi(sv.x)) * dd + bA.y;
        float r2 = (a2 + bflo(sv.y)) * dd + bA.z;
        float r3 = (a3 + bfhi(sv.y)) * dd + bA.w;
        float r4 = (a4 + bflo(sv.z)) * dd + bB.x;
        float r5 = (a5 + bfhi(sv.z)) * dd + bB.y;
        float r6 = (a6 + bflo(sv.w)) * dd + bB.z;
        float r7 = (a7 + bfhi(sv.w)) * dd + bB.w;
        if (RELU) {
            r0 = fmaxf(r0, 0.f); r1 = fmaxf(r1, 0.f); r2 = fmaxf(r2, 0.f); r3 = fmaxf(r3, 0.f);
            r4 = fmaxf(r4, 0.f); r5 = fmaxf(r5, 0.f); r6 = fmaxf(r6, 0.f); r7 = fmaxf(r7, 0.f);
        }
        packed = make_uint4(pk2bf(r0, r1), pk2bf(r2, r3), pk2bf(r4, r5), pk2bf(r6, r7));
    }
    lds_a[rl][h8 ^ (rl & 7)] = packed;          // XOR swizzle: banks spread
    __syncthreads();
    // ---- phase 2: GEMM on the block's 32 rows ----
    int hh = wv & 1, tt = wv >> 1;
    BF8 bq0, bq1, bq2, bq3;
    {
        const uint4* wp = (const uint4*)Wpk;
        bq0.q = wp[(4 * hh + 0) * 64 + lane];
        bq1.q = wp[(4 * hh + 1) * 64 + lane];
        bq2.q = wp[(4 * hh + 2) * 64 + lane];
        bq3.q = wp[(4 * hh + 3) * 64 + lane];
    }
    int mr = lane & 15, kq = lane >> 4, colb = lane & 15;
    int rloc = tt * 16 + mr;
    BF8 fa0, fa1;
    fa0.q = lds_a[rloc][kq ^ (rloc & 7)];
    fa1.q = lds_a[rloc][(kq + 4) ^ (rloc & 7)];
    f32x4 accA = {0.f, 0.f, 0.f, 0.f}, accB = accA;
    accA = __builtin_amdgcn_mfma_f32_16x16x32_bf16(fa0.v, bq0.v, accA, 0, 0, 0);
    accA = __builtin_amdgcn_mfma_f32_16x16x32_bf16(fa1.v, bq1.v, accA, 0, 0, 0);
    accB = __builtin_amdgcn_mfma_f32_16x16x32_bf16(fa0.v, bq2.v, accB, 0, 0, 0);
    accB = __builtin_amdgcn_mfma_f32_16x16x32_bf16(fa1.v, bq3.v, accB, 0, 0, 0);
    float b2x = 0.f, b2y = 0.f;
    if (OUT_F32) {
        b2x = bias2[(colb << 2) + (hh << 1)];
        b2y = bias2[(colb << 2) + (hh << 1) + 1];
    }
    int rowb = tt * 16 + (kq << 2);
#pragma unroll
    for (int i = 0; i < 4; ++i) {
        int sl = sbase + rowb + i;
        if (sl >= n) continue;
        int orow = perm[sl];
        if (OUT_F32) {
            float2 o = make_float2(accA[i] + b2x, accB[i] + b2y);
            *(float2*)((float*)outv + ((unsigned)orow << 6) + (colb << 2) + (hh << 1)) = o;
        } else {
            float sc = pdinv[sl];
            unsigned o = pk2bf(accA[i] * sc, accB[i] * sc);
            *(unsigned*)((unsigned short*)outv + ((unsigned)orow << 6) + (colb << 2) + (hh << 1)) = o;
        }
    }
}

extern "C" void kernel_launch(void* const* d_in, const int* in_sizes, int n_in,
                              void* d_out, int out_size, void* d_ws, size_t ws_size,
                              hipStream_t stream) {
    const float* x  = (const float*)d_in[0];
    const int*   ei = (const int*)d_in[1];   // [2][E] int32
    const float* W1 = (const float*)d_in[2];
    const float* b1 = (const float*)d_in[3];
    const float* W2 = (const float*)d_in[4];
    const float* b2 = (const float*)d_in[5];
    const float* Wl = (const float*)d_in[6];
    const float* bl = (const float*)d_in[7];
    float* out = (float*)d_out;

    const int n = in_sizes[0] / FEAT;   // 100000
    const int E = in_sizes[1] / 2;      // 1200000
    const int* src = ei;
    const int* dst = ei + E;

    const int B = 256;
    const int NB = (n + 511) >> 9;            // 196 buckets
    const int pblocks = (E + 4095) / 4096;
    const int fagg_blocks = NB * 16;          // 16 degree-bands x 32 slots per bucket

    char* w = (char*)d_ws;
    int*   bcnt     = (int*)w;              w += 256 * 4;
    float* pdinv    = (float*)w;            w += (size_t)n * 4;
    int*   perm     = (int*)w;              w += (size_t)n * 4;
    w = (char*)(((uintptr_t)w + 15) & ~(uintptr_t)15);
    int2*  pofs     = (int2*)w;             w += (size_t)n * 8;
    unsigned short* Wpk = (unsigned short*)w;  w += 3 * 4096 * 2;
    w = (char*)(((uintptr_t)w + 15) & ~(uintptr_t)15);
    unsigned* buckets = (unsigned*)w;       w += (size_t)NB * CAP * 4;
    int*   esrc     = (int*)w;              w += (size_t)NB * CAP * 4;
    unsigned short* bufA = (unsigned short*)w;  w += (size_t)n * FEAT * 2;  // Hs1
    unsigned short* bufB = (unsigned short*)w;                              // Hs3

    // ---- CSR build + fused layer-1 GEMM ----
    hipMemsetAsync(bcnt, 0, 256 * 4, stream);
    k_part<<<dim3(pblocks + 3), dim3(B), 0, stream>>>(src, dst, bcnt, buckets, E,
                                                      pblocks, W1, W2, Wl, Wpk);
    k_csr<<<dim3(NB), dim3(512), 0, stream>>>(buckets, bcnt, x, Wpk, bufA,
                                              esrc, perm, pofs, pdinv, n);

    // ---- fused layer-1 agg + layer-2 GEMM: Hs3 = (relu(agg(Hs1)+b1)@W2)*dinv ----
    k_fagg<true, false><<<dim3(fagg_blocks), dim3(B), 0, stream>>>(
        perm, pofs, pdinv, esrc, bufA, b1, Wpk + 4096, nullptr, bufB, NB, n);

    // ---- fused layer-2 agg + final linear: out = (agg(Hs3)+b2)@Wl + bl ----
    k_fagg<false, true><<<dim3(fagg_blocks), dim3(B), 0, stream>>>(
        perm, pofs, pdinv, esrc, bufB, b2, Wpk + 8192, bl, out, NB, n);
}